// Round 7
// baseline (520.613 us; speedup 1.0000x reference)
//
#include <hip/hip_runtime.h>

// ---------------------------------------------------------------------------
// DecoderBlock: B=2, T=2048, C=768, H=12, d=64
// GEMMs: bf16 MFMA, m97-style global_load_lds staging, BM templated (128/64).
// Attention: flash-style, 4 waves x 16 q-rows, KV tile 128 (fixed overheads --
// barriers/shuffles/defer-check -- amortized 2x vs KV=64); scale folded into
// Q-weights (log2 domain), last-iter-only causal mask, defer-max (T13),
// reg-staged K/V prefetch (T14). Causal: balanced two-pass (qt = 31-bx, bx).
// Preprocessing (8 transposes + 2 converts + 3 bias preps) fused in 1 kernel.
// ---------------------------------------------------------------------------

#define C_EMBD 768
#define NHEAD  12
#define HD     64
#define TB     2048
#define BB     2
#define MTOK   (BB*TB)   // 4096 tokens

typedef __bf16 bf16_8 __attribute__((ext_vector_type(8)));
typedef float  f32x4  __attribute__((ext_vector_type(4)));

#define EXP2(x) exp2f(x)

__device__ __forceinline__ unsigned short f2bf(float f) {
    union { __bf16 h; unsigned short u; } c;
    c.h = (__bf16)f;            // packed cvt (RNE)
    return c.u;
}

#define GLOAD_LDS16(gsrc, ldst) \
    __builtin_amdgcn_global_load_lds( \
        (const __attribute__((address_space(1))) void*)(gsrc), \
        (__attribute__((address_space(3))) void*)(ldst), 16, 0, 0)

// ---------------- fused preprocessing ----------------
__global__ __launch_bounds__(256) void k_preproc(
        const float* __restrict__ x,     const float* __restrict__ enc,
        const float* __restrict__ qkv_w, const float* __restrict__ proj_w,
        const float* __restrict__ caq_w, const float* __restrict__ cak_w,
        const float* __restrict__ cav_w, const float* __restrict__ cao_w,
        const float* __restrict__ fc_w,  const float* __restrict__ fc2_w,
        const float* __restrict__ qkv_b, const float* __restrict__ caq_b,
        const float* __restrict__ cak_b, const float* __restrict__ cav_b,
        unsigned short* __restrict__ xbf,  unsigned short* __restrict__ encbf,
        unsigned short* __restrict__ wqkv, unsigned short* __restrict__ wproj,
        unsigned short* __restrict__ wcq,  unsigned short* __restrict__ wck,
        unsigned short* __restrict__ wcv,  unsigned short* __restrict__ wco,
        unsigned short* __restrict__ wfc,  unsigned short* __restrict__ wfc2,
        float* __restrict__ bqkv, float* __restrict__ bkv, float* __restrict__ bcq,
        float sc2) {
    __shared__ float tile[32][33];
    int b = blockIdx.x, tid = threadIdx.x;
    if (b < 9216) {
        const float* W; unsigned short* Wt; int K, N, t; float sc; int slim;
        if      (b < 1728) { W=qkv_w;  Wt=wqkv;  K=768;  N=2304; t=b;      sc=sc2; slim=768; }
        else if (b < 2304) { W=proj_w; Wt=wproj; K=768;  N=768;  t=b-1728; sc=1.f; slim=0;   }
        else if (b < 2880) { W=caq_w;  Wt=wcq;   K=768;  N=768;  t=b-2304; sc=sc2; slim=768; }
        else if (b < 3456) { W=cak_w;  Wt=wck;   K=768;  N=768;  t=b-2880; sc=1.f; slim=0;   }
        else if (b < 4032) { W=cav_w;  Wt=wcv;   K=768;  N=768;  t=b-3456; sc=1.f; slim=0;   }
        else if (b < 4608) { W=cao_w;  Wt=wco;   K=768;  N=768;  t=b-4032; sc=1.f; slim=0;   }
        else if (b < 6912) { W=fc_w;   Wt=wfc;   K=768;  N=3072; t=b-4608; sc=1.f; slim=0;   }
        else               { W=fc2_w;  Wt=wfc2;  K=3072; N=768;  t=b-6912; sc=1.f; slim=0;   }
        int ntx = N >> 5;
        int n0 = (t % ntx) * 32, k0 = (t / ntx) * 32;
        int tx = tid & 31, ty = tid >> 5;
#pragma unroll
        for (int i = 0; i < 4; ++i)
            tile[ty + 8*i][tx] = W[(size_t)(k0 + ty + 8*i) * N + n0 + tx];
        __syncthreads();
#pragma unroll
        for (int i = 0; i < 4; ++i) {
            int nrow = n0 + ty + 8*i;
            float s = (nrow < slim) ? sc : 1.0f;
            Wt[(size_t)nrow * K + k0 + tx] = f2bf(tile[tx][ty + 8*i] * s);
        }
    } else if (b < 15360) {
        int b2 = b - 9216;
        const float* src = (b2 < 3072) ? x   : enc;
        unsigned short* dst = (b2 < 3072) ? xbf : encbf;
        int i = (b2 < 3072 ? b2 : b2 - 3072) * 256 + tid;
        float4 v = ((const float4*)src)[i];
        ushort4 o;
        o.x = f2bf(v.x); o.y = f2bf(v.y); o.z = f2bf(v.z); o.w = f2bf(v.w);
        ((ushort4*)dst)[i] = o;
    } else {
        int b3 = b - 15360;
        if (b3 < 9) {
            int i = b3 * 256 + tid;
            if (i < 2304) bqkv[i] = qkv_b[i] * (i < 768 ? sc2 : 1.0f);
        } else if (b3 < 12) {
            int i = (b3 - 9) * 256 + tid;
            if (i < 768) { bkv[i] = cak_b[i]; bkv[768 + i] = cav_b[i]; }
        } else {
            int i = (b3 - 12) * 256 + tid;
            if (i < 768) bcq[i] = caq_b[i] * sc2;
        }
    }
}

// ---------------- GEMM: C[MxN] = A[MxK] @ Bt[NxK]^T + bias (+res)(+relu) ----
template<int BM, bool OUT_BF16, bool ADD_RES, bool RELU>
__global__ __launch_bounds__(256) void k_gemm_bt(
        const unsigned short* __restrict__ A,
        const unsigned short* __restrict__ Bt,
        const float* __restrict__ bias,
        const float* __restrict__ res,
        void* __restrict__ Cout,
        int M, int N, int K) {
    constexpr int MF = BM / 32;              // m-fragments per wave
    __shared__ unsigned short As[BM * 32];   // linear: row*32 + col
    __shared__ unsigned short Bs[128 * 32];
    int tid  = threadIdx.x;
    int lane = tid & 63, wave = tid >> 6;
    int l16 = lane & 15, lg = lane >> 4;
    int wm = (wave >> 1) * (BM / 2), wn = (wave & 1) * 64;
    int bm = blockIdx.x * BM, bn = blockIdx.y * 128;

    f32x4 acc[MF][4] = {};

    for (int k0 = 0; k0 < K; k0 += 32) {
        __syncthreads();
#pragma unroll
        for (int i = 0; i < BM / 64; ++i) {
            int chunk = i * 256 + tid;
            GLOAD_LDS16(A + (size_t)(bm + (chunk >> 2)) * K + k0 + (chunk & 3) * 8,
                        As + (size_t)(i * 256 + wave * 64) * 8);
        }
#pragma unroll
        for (int i = 0; i < 2; ++i) {
            int chunk = i * 256 + tid;
            GLOAD_LDS16(Bt + (size_t)(bn + (chunk >> 2)) * K + k0 + (chunk & 3) * 8,
                        Bs + (size_t)(i * 256 + wave * 64) * 8);
        }
        __syncthreads();   // drains vmcnt(0) -> LDS ready
        bf16_8 af[MF], bfr[4];
#pragma unroll
        for (int m = 0; m < MF; ++m)
            af[m]  = *(const bf16_8*)(As + (size_t)(wm + m*16 + l16) * 32 + lg * 8);
#pragma unroll
        for (int n = 0; n < 4; ++n)
            bfr[n] = *(const bf16_8*)(Bs + (size_t)(wn + n*16 + l16) * 32 + lg * 8);
#pragma unroll
        for (int m = 0; m < MF; ++m)
#pragma unroll
            for (int n = 0; n < 4; ++n)
                acc[m][n] = __builtin_amdgcn_mfma_f32_16x16x32_bf16(af[m], bfr[n], acc[m][n], 0, 0, 0);
    }

#pragma unroll
    for (int m = 0; m < MF; ++m) {
#pragma unroll
        for (int n = 0; n < 4; ++n) {
            int col = bn + wn + n*16 + l16;
            float bv = bias[col];
#pragma unroll
            for (int r = 0; r < 4; ++r) {
                int row = bm + wm + m*16 + lg*4 + r;   // C/D: col=lane&15, row=(lane>>4)*4+reg
                float v = acc[m][n][r] + bv;
                if (ADD_RES) v += res[(size_t)row * N + col];
                if (RELU)    v = fmaxf(v, 0.f);
                if (OUT_BF16) ((unsigned short*)Cout)[(size_t)row * N + col] = f2bf(v);
                else          ((float*)Cout)[(size_t)row * N + col] = v;
            }
        }
    }
}

// ---------------- Flash attention: 4 waves x 16 q-rows, KV tile 128 ---------
// Q pre-scaled by 0.125*log2(e). CAUSAL: balanced two-pass, grid.x = 16,
// block bx does q-tile (31-bx) then (bx) -> uniform 17 iterations per block.
template<bool CAUSAL>
__global__ __launch_bounds__(256) void k_attn(
        const unsigned short* __restrict__ Qp,
        const unsigned short* __restrict__ Kp,
        const unsigned short* __restrict__ Vp,
        unsigned short* __restrict__ Yp,
        int strideQ, int strideKV) {
    __shared__ __bf16 Ks[128][72];      // K tile row-major [kpos][d]
    __shared__ __bf16 Vt[64][136];      // V tile transposed [d][kpos]
    __shared__ __bf16 Ps[4][16][136];   // per-wave P tile (wave-private)
    int tid  = threadIdx.x;
    int lane = tid & 63, wave = tid >> 6;
    int l16 = lane & 15, lg = lane >> 4;
    int bh = blockIdx.y;
    int b = bh / NHEAD, h = bh - b * NHEAD;

    const unsigned short* Qb = Qp + (size_t)b * TB * strideQ  + h * HD;
    const unsigned short* Kb = Kp + (size_t)b * TB * strideKV + h * HD;
    const unsigned short* Vb = Vp + (size_t)b * TB * strideKV + h * HD;

    // all-ones B fragment: row-sum of P via MFMA
    bf16_8 vones;
#pragma unroll
    for (int j = 0; j < 8; ++j) vones[j] = (__bf16)1.0f;

    // staging assignments (constant per thread)
    int kr = tid >> 3, kc = (tid & 7) * 8;     // K: rows kr+{0,32,64,96}, cols kc..
    int vk2 = (tid & 31) * 2;                  // V: even kpos pair (both 64-halves)
    int vd0 = (tid >> 5) * 8;                  // V: d block of 8
    const size_t stepKV = (size_t)128 * strideKV;

    const int npass = CAUSAL ? 2 : 1;
    for (int pass = 0; pass < npass; ++pass) {
        int qt = CAUSAL ? (pass == 0 ? (TB/64 - 1 - (int)blockIdx.x) : (int)blockIdx.x)
                        : (int)blockIdx.x;
        int wq = qt * 64 + wave * 16;          // this wave's q strip start

        // Q fragments (A-operand: row=l16, k=lg*8..)
        bf16_8 qf0 = *(const bf16_8*)(Qb + (size_t)(wq + l16) * strideQ + lg * 8);
        bf16_8 qf1 = *(const bf16_8*)(Qb + (size_t)(wq + l16) * strideQ + 32 + lg * 8);

        const unsigned short* gK = Kb + (size_t)kr  * strideKV + kc;
        const unsigned short* gV = Vb + (size_t)vk2 * strideKV + vd0;

        // prologue: iteration-0 tile into registers (V pre-packed)
        int4 kA[4];
        unsigned vp[16];
#pragma unroll
        for (int q = 0; q < 4; ++q)
            kA[q] = *(const int4*)(gK + (size_t)(q * 32) * strideKV);
#pragma unroll
        for (int hh = 0; hh < 2; ++hh) {
            int4 va = *(const int4*)(gV + (size_t)(hh * 64)     * strideKV);
            int4 vb2 = *(const int4*)(gV + (size_t)(hh * 64 + 1) * strideKV);
            const unsigned short* pa = (const unsigned short*)&va;
            const unsigned short* pb = (const unsigned short*)&vb2;
#pragma unroll
            for (int j = 0; j < 8; ++j)
                vp[hh*8 + j] = (unsigned)pa[j] | ((unsigned)pb[j] << 16);
        }

        f32x4 o[4] = {};
        float m_run[4], l_run[4];              // log2 domain
#pragma unroll
        for (int r = 0; r < 4; ++r) { m_run[r] = -1e30f; l_run[r] = 0.f; }

        int nIter = CAUSAL ? ((qt >> 1) + 1) : (TB / 128);
        for (int it = 0; it < nIter; ++it) {
            __syncthreads();                   // prev-iter LDS reads done
#pragma unroll
            for (int q = 0; q < 4; ++q)
                *(int4*)(&Ks[kr + q * 32][kc]) = kA[q];
#pragma unroll
            for (int hh = 0; hh < 2; ++hh)
#pragma unroll
                for (int j = 0; j < 8; ++j)
                    *(unsigned*)(&Vt[vd0 + j][hh*64 + vk2]) = vp[hh*8 + j];
            __syncthreads();                   // LDS ready

            // T14: issue next iteration's global loads; hide under compute
            if (it + 1 < nIter) {
                gK += stepKV; gV += stepKV;
#pragma unroll
                for (int q = 0; q < 4; ++q)
                    kA[q] = *(const int4*)(gK + (size_t)(q * 32) * strideKV);
#pragma unroll
                for (int hh = 0; hh < 2; ++hh) {
                    int4 va = *(const int4*)(gV + (size_t)(hh * 64)     * strideKV);
                    int4 vb2 = *(const int4*)(gV + (size_t)(hh * 64 + 1) * strideKV);
                    const unsigned short* pa = (const unsigned short*)&va;
                    const unsigned short* pb = (const unsigned short*)&vb2;
#pragma unroll
                    for (int j = 0; j < 8; ++j)
                        vp[hh*8 + j] = (unsigned)pa[j] | ((unsigned)pb[j] << 16);
                }
            }

            // S = Q K^T  (16 x 128 per wave), log2 domain
            f32x4 s[8];
#pragma unroll
            for (int n = 0; n < 8; ++n) {
                f32x4 z = {};
                bf16_8 kf0 = *(const bf16_8*)(&Ks[n*16 + l16][lg*8]);
                bf16_8 kf1 = *(const bf16_8*)(&Ks[n*16 + l16][32 + lg*8]);
                z = __builtin_amdgcn_mfma_f32_16x16x32_bf16(qf0, kf0, z, 0, 0, 0);
                z = __builtin_amdgcn_mfma_f32_16x16x32_bf16(qf1, kf1, z, 0, 0, 0);
                s[n] = z;
            }
            // causal mask: only the last iteration can touch the diagonal
            if (CAUSAL && it == nIter - 1) {
#pragma unroll
                for (int n = 0; n < 8; ++n)
#pragma unroll
                    for (int r = 0; r < 4; ++r)
                        if (it*128 + n*16 + l16 > wq + lg*4 + r) s[n][r] = -1e30f;
            }
            // row max (16-lane butterfly)
            float mx[4];
#pragma unroll
            for (int r = 0; r < 4; ++r) {
                mx[r] = fmaxf(fmaxf(s[0][r], s[1][r]), fmaxf(s[2][r], s[3][r]));
                mx[r] = fmaxf(mx[r], fmaxf(fmaxf(s[4][r], s[5][r]), fmaxf(s[6][r], s[7][r])));
            }
#pragma unroll
            for (int off = 1; off < 16; off <<= 1)
#pragma unroll
                for (int r = 0; r < 4; ++r)
                    mx[r] = fmaxf(mx[r], __shfl_xor(mx[r], off, 64));
            // T13 defer-max: rescale only when max grew by > 8 (log2)
            bool big = (mx[0] > m_run[0] + 8.f) | (mx[1] > m_run[1] + 8.f) |
                       (mx[2] > m_run[2] + 8.f) | (mx[3] > m_run[3] + 8.f);
            if (__any(big)) {
#pragma unroll
                for (int r = 0; r < 4; ++r) {
                    float mnew = fmaxf(m_run[r], mx[r]);
                    float sf = EXP2(m_run[r] - mnew);
                    m_run[r] = mnew;
                    l_run[r] *= sf;
#pragma unroll
                    for (int n = 0; n < 4; ++n) o[n][r] *= sf;
                }
            }
            // P = 2^(s - m) -> LDS bf16 (wave-private; lgkmcnt orders)
#pragma unroll
            for (int n = 0; n < 8; ++n)
#pragma unroll
                for (int r = 0; r < 4; ++r)
                    Ps[wave][lg*4 + r][n*16 + l16] = (__bf16)EXP2(s[n][r] - m_run[r]);

            // O += P @ V ; row-sum of P via ones-MFMA
            f32x4 zsum = {};
#pragma unroll
            for (int kk = 0; kk < 4; ++kk) {
                bf16_8 pa = *(const bf16_8*)(&Ps[wave][l16][kk*32 + lg*8]);
                zsum = __builtin_amdgcn_mfma_f32_16x16x32_bf16(pa, vones, zsum, 0, 0, 0);
#pragma unroll
                for (int n = 0; n < 4; ++n) {
                    bf16_8 vf = *(const bf16_8*)(&Vt[n*16 + l16][kk*32 + lg*8]);
                    o[n] = __builtin_amdgcn_mfma_f32_16x16x32_bf16(pa, vf, o[n], 0, 0, 0);
                }
            }
#pragma unroll
            for (int r = 0; r < 4; ++r) l_run[r] += zsum[r];
        }

        // epilogue: O / l -> Y (bf16, [token][h*64+d])
#pragma unroll
        for (int r = 0; r < 4; ++r) {
            float rl = 1.0f / l_run[r];
            int token = b * TB + wq + lg*4 + r;
#pragma unroll
            for (int n = 0; n < 4; ++n)
                Yp[(size_t)token * C_EMBD + h * HD + n*16 + l16] = f2bf(o[n][r] * rl);
        }
    }
}

// ---------------- LayerNorm over C=768, one block per row ----------------
template<bool WF32, bool WBF16>
__global__ __launch_bounds__(256) void k_ln(const float* __restrict__ in,
                                            const float* __restrict__ g,
                                            const float* __restrict__ bb,
                                            float* __restrict__ outf,
                                            unsigned short* __restrict__ outb) {
    int row = blockIdx.x;
    const float* x = in + (size_t)row * C_EMBD;
    float v[3], s1 = 0.f, s2 = 0.f;
#pragma unroll
    for (int i = 0; i < 3; ++i) {
        v[i] = x[threadIdx.x + i * 256];
        s1 += v[i];
        s2 += v[i] * v[i];
    }
#pragma unroll
    for (int off = 1; off < 64; off <<= 1) {
        s1 += __shfl_xor(s1, off, 64);
        s2 += __shfl_xor(s2, off, 64);
    }
    __shared__ float red[8];
    int wave = threadIdx.x >> 6, lane = threadIdx.x & 63;
    if (lane == 0) { red[wave] = s1; red[4 + wave] = s2; }
    __syncthreads();
    s1 = red[0] + red[1] + red[2] + red[3];
    s2 = red[4] + red[5] + red[6] + red[7];
    float mu  = s1 * (1.f / C_EMBD);
    float var = s2 * (1.f / C_EMBD) - mu * mu;
    float rs  = rsqrtf(var + 1e-5f);
#pragma unroll
    for (int i = 0; i < 3; ++i) {
        int c = threadIdx.x + i * 256;
        float y = (v[i] - mu) * rs * g[c] + bb[c];
        if (WF32)  outf[(size_t)row * C_EMBD + c] = y;
        if (WBF16) outb[(size_t)row * C_EMBD + c] = f2bf(y);
    }
}

// ---------------------------------------------------------------------------
extern "C" void kernel_launch(void* const* d_in, const int* in_sizes, int n_in,
                              void* d_out, int out_size, void* d_ws, size_t ws_size,
                              hipStream_t stream) {
    (void)in_sizes; (void)n_in; (void)out_size; (void)ws_size;
    const float* x      = (const float*)d_in[0];
    const float* enc    = (const float*)d_in[1];
    const float* ln1_g  = (const float*)d_in[2];
    const float* ln1_b  = (const float*)d_in[3];
    const float* qkv_w  = (const float*)d_in[4];
    const float* qkv_b  = (const float*)d_in[5];
    const float* proj_w = (const float*)d_in[6];
    const float* proj_b = (const float*)d_in[7];
    const float* ln2_g  = (const float*)d_in[8];
    const float* ln2_b  = (const float*)d_in[9];
    const float* caq_w  = (const float*)d_in[10];
    const float* caq_b  = (const float*)d_in[11];
    const float* cak_w  = (const float*)d_in[12];
    const float* cak_b  = (const float*)d_in[13];
    const float* cav_w  = (const float*)d_in[14];
    const float* cav_b  = (const float*)d_in[15];
    const float* cao_w  = (const float*)d_in[16];
    const float* cao_b  = (const float*)d_in[17];
    const float* ln3_g  = (const float*)d_in[18];
    const float* ln3_b  = (const float*)d_in[19];
    const float* fc_w   = (const float*)d_in[20];
    const float* fc_b   = (const float*)d_in[21];
    const float* fc2_w  = (const float*)d_in[22];
    const float* fc2_b  = (const float*)d_in[23];
    float* out = (float*)d_out;

    char* ws = (char*)d_ws;
    auto us = [&](size_t off) { return (unsigned short*)(ws + off); };
    auto fl = [&](size_t off) { return (float*)(ws + off); };

    // arena offsets (bytes, all 256-aligned)
    const size_t O_WQKV  = 0;            // 2304x768 bf16
    const size_t O_WPROJ = 3538944;      // 768x768
    const size_t O_WCQ   = 4718592;
    const size_t O_WCK   = 5898240;      // [Wck|Wcv] contiguous -> 1536x768
    const size_t O_WCV   = 7077888;
    const size_t O_WCO   = 8257536;
    const size_t O_WFC   = 9437184;      // 3072x768
    const size_t O_WFC2  = 14155776;     // 768x3072
    const size_t O_XBF   = 18874368;     // 4096x768 bf16
    const size_t O_ENCBF = 25165824;
    const size_t O_QKVBF = 31457280;     // 4096x2304 bf16 (later cq + [ck|cv])
    const size_t O_Q2    = O_QKVBF;
    const size_t O_KV2   = O_QKVBF + 6291456;   // 4096x1536 bf16 combined
    const size_t O_YBF   = 50331648;     // 4096x768 bf16 (attn out, reused)
    const size_t O_RESF  = 56623104;     // 4096x768 f32 (pre-LN, reused 3x)
    const size_t O_X1F   = 69206016;
    const size_t O_X1BF  = 81788928;
    const size_t O_X2F   = 88080384;
    const size_t O_X2BF  = 100663296;
    const size_t O_HBF   = 106954752;    // 4096x3072 bf16 (dead until step 11;
    const size_t O_BKV   = O_HBF;        //  bias staging lives here early)
    const size_t O_BQKV  = O_HBF + 8192;
    const size_t O_BCQ   = O_HBF + 20480;

    const float SC2 = 0.125f * 1.44269504f;   // scale * log2(e), folded into Q path

    // 1+2) fused preprocessing: all transposes + converts + bias staging
    k_preproc<<<15375, 256, 0, stream>>>(
        x, enc, qkv_w, proj_w, caq_w, cak_w, cav_w, cao_w, fc_w, fc2_w,
        qkv_b, caq_b, cak_b, cav_b,
        us(O_XBF), us(O_ENCBF),
        us(O_WQKV), us(O_WPROJ), us(O_WCQ), us(O_WCK),
        us(O_WCV), us(O_WCO), us(O_WFC), us(O_WFC2),
        fl(O_BQKV), fl(O_BKV), fl(O_BCQ), SC2);

    // 3) qkv = x @ Wqkv' + b'      (bf16 out; Q cols pre-scaled)
    k_gemm_bt<128, true,  false, false><<<dim3(32, 18), 256, 0, stream>>>(
        us(O_XBF), us(O_WQKV), fl(O_BQKV), nullptr, us(O_QKVBF), MTOK, 2304, 768);
    // 4) self-attention (causal, balanced two-pass: grid.x = 16)
    k_attn<true><<<dim3(TB/128, BB*NHEAD), 256, 0, stream>>>(
        us(O_QKVBF), us(O_QKVBF) + 768, us(O_QKVBF) + 1536, us(O_YBF), 2304, 2304);
    // 5) proj + bias + residual(x) -> fp32
    k_gemm_bt<64, false, true,  false><<<dim3(64, 6), 256, 0, stream>>>(
        us(O_YBF), us(O_WPROJ), proj_b, x, fl(O_RESF), MTOK, 768, 768);
    // 6) LN1 -> x1 (f32 + bf16)
    k_ln<true, true><<<MTOK, 256, 0, stream>>>(fl(O_RESF), ln1_g, ln1_b, fl(O_X1F), us(O_X1BF));
    // 7) cross-attn projections: cq (pre-scaled) ; [ck|cv] fused (N=1536)
    k_gemm_bt<64, true,  false, false><<<dim3(64, 6), 256, 0, stream>>>(
        us(O_X1BF),  us(O_WCQ), fl(O_BCQ), nullptr, us(O_Q2), MTOK, 768, 768);
    k_gemm_bt<128, true,  false, false><<<dim3(32, 12), 256, 0, stream>>>(
        us(O_ENCBF), us(O_WCK), fl(O_BKV), nullptr, us(O_KV2), MTOK, 1536, 768);
    // 8) cross-attention (non-causal): K at col 0, V at col 768, stride 1536
    k_attn<false><<<dim3(TB/64, BB*NHEAD), 256, 0, stream>>>(
        us(O_Q2), us(O_KV2), us(O_KV2) + 768, us(O_YBF), 768, 1536);
    // 9) ca_o + bias + residual(x1) -> fp32
    k_gemm_bt<64, false, true,  false><<<dim3(64, 6), 256, 0, stream>>>(
        us(O_YBF), us(O_WCO), cao_b, fl(O_X1F), fl(O_RESF), MTOK, 768, 768);
    // 10) LN2 -> x2
    k_ln<true, true><<<MTOK, 256, 0, stream>>>(fl(O_RESF), ln2_g, ln2_b, fl(O_X2F), us(O_X2BF));
    // 11) fc + bias + relu -> bf16
    k_gemm_bt<128, true,  false, true ><<<dim3(32, 24), 256, 0, stream>>>(
        us(O_X2BF), us(O_WFC), fc_b, nullptr, us(O_HBF), MTOK, 3072, 768);
    // 12) fc2 + bias + residual(x2) -> fp32
    k_gemm_bt<64, false, true,  false><<<dim3(64, 6), 256, 0, stream>>>(
        us(O_HBF), us(O_WFC2), fc2_b, fl(O_X2F), fl(O_RESF), MTOK, 768, 3072);
    // 13) LN3 -> out (fp32 only)
    k_ln<true, false><<<MTOK, 256, 0, stream>>>(fl(O_RESF), ln3_g, ln3_b, out, nullptr);
}

// Round 8
// 502.268 us; speedup vs baseline: 1.0365x; 1.0365x over previous
//
#include <hip/hip_runtime.h>

// ---------------------------------------------------------------------------
// DecoderBlock: B=2, T=2048, C=768, H=12, d=64
// GEMMs: bf16 MFMA, m97-style global_load_lds staging, BM templated (128/64).
// Attention: flash-style, 4 waves x 16 q-rows, KV tile 64, double-buffered
// LDS with ONE barrier/tile; scale folded into Q-weights (log2 domain),
// diagonal-only causal mask, defer-max (T13), reg-staged prefetch (T14),
// native v_exp_f32 via builtin. Causal: reversed-qt (tail-first).
// Preprocessing (8 transposes + 2 converts + 3 bias preps) fused in 1 kernel.
// ---------------------------------------------------------------------------

#define C_EMBD 768
#define NHEAD  12
#define HD     64
#define TB     2048
#define BB     2
#define MTOK   (BB*TB)   // 4096 tokens

typedef __bf16 bf16_8 __attribute__((ext_vector_type(8)));
typedef float  f32x4  __attribute__((ext_vector_type(4)));

#if __has_builtin(__builtin_amdgcn_exp2f)
#define EXP2(x) __builtin_amdgcn_exp2f(x)
#else
#define EXP2(x) exp2f(x)
#endif

__device__ __forceinline__ unsigned short f2bf(float f) {
    union { __bf16 h; unsigned short u; } c;
    c.h = (__bf16)f;            // packed cvt (RNE)
    return c.u;
}

#define GLOAD_LDS16(gsrc, ldst) \
    __builtin_amdgcn_global_load_lds( \
        (const __attribute__((address_space(1))) void*)(gsrc), \
        (__attribute__((address_space(3))) void*)(ldst), 16, 0, 0)

// ---------------- fused preprocessing ----------------
__global__ __launch_bounds__(256) void k_preproc(
        const float* __restrict__ x,     const float* __restrict__ enc,
        const float* __restrict__ qkv_w, const float* __restrict__ proj_w,
        const float* __restrict__ caq_w, const float* __restrict__ cak_w,
        const float* __restrict__ cav_w, const float* __restrict__ cao_w,
        const float* __restrict__ fc_w,  const float* __restrict__ fc2_w,
        const float* __restrict__ qkv_b, const float* __restrict__ caq_b,
        const float* __restrict__ cak_b, const float* __restrict__ cav_b,
        unsigned short* __restrict__ xbf,  unsigned short* __restrict__ encbf,
        unsigned short* __restrict__ wqkv, unsigned short* __restrict__ wproj,
        unsigned short* __restrict__ wcq,  unsigned short* __restrict__ wck,
        unsigned short* __restrict__ wcv,  unsigned short* __restrict__ wco,
        unsigned short* __restrict__ wfc,  unsigned short* __restrict__ wfc2,
        float* __restrict__ bqkv, float* __restrict__ bkv, float* __restrict__ bcq,
        float sc2) {
    __shared__ float tile[32][33];
    int b = blockIdx.x, tid = threadIdx.x;
    if (b < 9216) {
        const float* W; unsigned short* Wt; int K, N, t; float sc; int slim;
        if      (b < 1728) { W=qkv_w;  Wt=wqkv;  K=768;  N=2304; t=b;      sc=sc2; slim=768; }
        else if (b < 2304) { W=proj_w; Wt=wproj; K=768;  N=768;  t=b-1728; sc=1.f; slim=0;   }
        else if (b < 2880) { W=caq_w;  Wt=wcq;   K=768;  N=768;  t=b-2304; sc=sc2; slim=768; }
        else if (b < 3456) { W=cak_w;  Wt=wck;   K=768;  N=768;  t=b-2880; sc=1.f; slim=0;   }
        else if (b < 4032) { W=cav_w;  Wt=wcv;   K=768;  N=768;  t=b-3456; sc=1.f; slim=0;   }
        else if (b < 4608) { W=cao_w;  Wt=wco;   K=768;  N=768;  t=b-4032; sc=1.f; slim=0;   }
        else if (b < 6912) { W=fc_w;   Wt=wfc;   K=768;  N=3072; t=b-4608; sc=1.f; slim=0;   }
        else               { W=fc2_w;  Wt=wfc2;  K=3072; N=768;  t=b-6912; sc=1.f; slim=0;   }
        int ntx = N >> 5;
        int n0 = (t % ntx) * 32, k0 = (t / ntx) * 32;
        int tx = tid & 31, ty = tid >> 5;
#pragma unroll
        for (int i = 0; i < 4; ++i)
            tile[ty + 8*i][tx] = W[(size_t)(k0 + ty + 8*i) * N + n0 + tx];
        __syncthreads();
#pragma unroll
        for (int i = 0; i < 4; ++i) {
            int nrow = n0 + ty + 8*i;
            float s = (nrow < slim) ? sc : 1.0f;
            Wt[(size_t)nrow * K + k0 + tx] = f2bf(tile[tx][ty + 8*i] * s);
        }
    } else if (b < 15360) {
        int b2 = b - 9216;
        const float* src = (b2 < 3072) ? x   : enc;
        unsigned short* dst = (b2 < 3072) ? xbf : encbf;
        int i = (b2 < 3072 ? b2 : b2 - 3072) * 256 + tid;
        float4 v = ((const float4*)src)[i];
        ushort4 o;
        o.x = f2bf(v.x); o.y = f2bf(v.y); o.z = f2bf(v.z); o.w = f2bf(v.w);
        ((ushort4*)dst)[i] = o;
    } else {
        int b3 = b - 15360;
        if (b3 < 9) {
            int i = b3 * 256 + tid;
            if (i < 2304) bqkv[i] = qkv_b[i] * (i < 768 ? sc2 : 1.0f);
        } else if (b3 < 12) {
            int i = (b3 - 9) * 256 + tid;
            if (i < 768) { bkv[i] = cak_b[i]; bkv[768 + i] = cav_b[i]; }
        } else {
            int i = (b3 - 12) * 256 + tid;
            if (i < 768) bcq[i] = caq_b[i] * sc2;
        }
    }
}

// ---------------- GEMM: C[MxN] = A[MxK] @ Bt[NxK]^T + bias (+res)(+relu) ----
template<int BM, bool OUT_BF16, bool ADD_RES, bool RELU>
__global__ __launch_bounds__(256) void k_gemm_bt(
        const unsigned short* __restrict__ A,
        const unsigned short* __restrict__ Bt,
        const float* __restrict__ bias,
        const float* __restrict__ res,
        void* __restrict__ Cout,
        int M, int N, int K) {
    constexpr int MF = BM / 32;              // m-fragments per wave
    __shared__ unsigned short As[BM * 32];   // linear: row*32 + col
    __shared__ unsigned short Bs[128 * 32];
    int tid  = threadIdx.x;
    int lane = tid & 63, wave = tid >> 6;
    int l16 = lane & 15, lg = lane >> 4;
    int wm = (wave >> 1) * (BM / 2), wn = (wave & 1) * 64;
    int bm = blockIdx.x * BM, bn = blockIdx.y * 128;

    f32x4 acc[MF][4] = {};

    for (int k0 = 0; k0 < K; k0 += 32) {
        __syncthreads();
#pragma unroll
        for (int i = 0; i < BM / 64; ++i) {
            int chunk = i * 256 + tid;
            GLOAD_LDS16(A + (size_t)(bm + (chunk >> 2)) * K + k0 + (chunk & 3) * 8,
                        As + (size_t)(i * 256 + wave * 64) * 8);
        }
#pragma unroll
        for (int i = 0; i < 2; ++i) {
            int chunk = i * 256 + tid;
            GLOAD_LDS16(Bt + (size_t)(bn + (chunk >> 2)) * K + k0 + (chunk & 3) * 8,
                        Bs + (size_t)(i * 256 + wave * 64) * 8);
        }
        __syncthreads();   // drains vmcnt(0) -> LDS ready
        bf16_8 af[MF], bfr[4];
#pragma unroll
        for (int m = 0; m < MF; ++m)
            af[m]  = *(const bf16_8*)(As + (size_t)(wm + m*16 + l16) * 32 + lg * 8);
#pragma unroll
        for (int n = 0; n < 4; ++n)
            bfr[n] = *(const bf16_8*)(Bs + (size_t)(wn + n*16 + l16) * 32 + lg * 8);
#pragma unroll
        for (int m = 0; m < MF; ++m)
#pragma unroll
            for (int n = 0; n < 4; ++n)
                acc[m][n] = __builtin_amdgcn_mfma_f32_16x16x32_bf16(af[m], bfr[n], acc[m][n], 0, 0, 0);
    }

#pragma unroll
    for (int m = 0; m < MF; ++m) {
#pragma unroll
        for (int n = 0; n < 4; ++n) {
            int col = bn + wn + n*16 + l16;
            float bv = bias[col];
#pragma unroll
            for (int r = 0; r < 4; ++r) {
                int row = bm + wm + m*16 + lg*4 + r;   // C/D: col=lane&15, row=(lane>>4)*4+reg
                float v = acc[m][n][r] + bv;
                if (ADD_RES) v += res[(size_t)row * N + col];
                if (RELU)    v = fmaxf(v, 0.f);
                if (OUT_BF16) ((unsigned short*)Cout)[(size_t)row * N + col] = f2bf(v);
                else          ((float*)Cout)[(size_t)row * N + col] = v;
            }
        }
    }
}

// ---------------- Flash attention: 4 waves x 16 q-rows, KV tile 64 ----------
// Double-buffered LDS, ONE barrier per tile. Q pre-scaled by 0.125*log2(e).
template<bool CAUSAL>
__global__ __launch_bounds__(256) void k_attn(
        const unsigned short* __restrict__ Qp,
        const unsigned short* __restrict__ Kp,
        const unsigned short* __restrict__ Vp,
        unsigned short* __restrict__ Yp,
        int strideQ, int strideKV) {
    __shared__ __bf16 Ks[2][64][72];   // K tile row-major [buf][kpos][d]
    __shared__ __bf16 Vt[2][64][72];   // V tile transposed [buf][d][kpos]
    __shared__ __bf16 Ps[4][16][72];   // per-wave P tile (wave-private)
    int tid  = threadIdx.x;
    int lane = tid & 63, wave = tid >> 6;
    int l16 = lane & 15, lg = lane >> 4;
    int bh = blockIdx.y;
    int b = bh / NHEAD, h = bh - b * NHEAD;
    // causal: heaviest q-tiles first (tail-balance)
    int qt = CAUSAL ? (gridDim.x - 1 - blockIdx.x) : blockIdx.x;
    int wq = qt * 64 + wave * 16;              // this wave's q strip start

    const unsigned short* Qb = Qp + (size_t)b * TB * strideQ  + h * HD;
    const unsigned short* Kb = Kp + (size_t)b * TB * strideKV + h * HD;
    const unsigned short* Vb = Vp + (size_t)b * TB * strideKV + h * HD;

    // Q fragments (A-operand: row=l16, k=lg*8..)
    bf16_8 qf0 = *(const bf16_8*)(Qb + (size_t)(wq + l16) * strideQ + lg * 8);
    bf16_8 qf1 = *(const bf16_8*)(Qb + (size_t)(wq + l16) * strideQ + 32 + lg * 8);

    // all-ones B fragment: row-sum of P via MFMA
    bf16_8 vones;
#pragma unroll
    for (int j = 0; j < 8; ++j) vones[j] = (__bf16)1.0f;

    // staging assignments (constant per thread)
    int kr = tid >> 3, kc = (tid & 7) * 8;     // K: rows kr, kr+32; 8 cols at kc
    int vk2 = (tid & 31) * 2;                  // V: even k row pair
    int vd0 = (tid >> 5) * 8;                  // V: d block of 8
    const size_t stepKV = (size_t)64 * strideKV;

    const unsigned short* gK0 = Kb + (size_t)kr  * strideKV + kc;
    const unsigned short* gK1 = gK0 + (size_t)32 * strideKV;
    const unsigned short* gV0 = Vb + (size_t)vk2 * strideKV + vd0;
    const unsigned short* gV1 = gV0 + strideKV;

    // prologue: load tile 0 into registers, write buffer 0, one barrier
    int4 kA = *(const int4*)gK0;
    int4 kB = *(const int4*)gK1;
    unsigned vp[8];
    {
        int4 va = *(const int4*)gV0, vb2 = *(const int4*)gV1;
        const unsigned short* pa = (const unsigned short*)&va;
        const unsigned short* pb = (const unsigned short*)&vb2;
#pragma unroll
        for (int j = 0; j < 8; ++j) vp[j] = (unsigned)pa[j] | ((unsigned)pb[j] << 16);
    }
    *(int4*)(&Ks[0][kr][kc])      = kA;
    *(int4*)(&Ks[0][kr + 32][kc]) = kB;
#pragma unroll
    for (int j = 0; j < 8; ++j)
        *(unsigned*)(&Vt[0][vd0 + j][vk2]) = vp[j];
    __syncthreads();

    f32x4 o[4] = {};
    float m_run[4], l_run[4];                  // log2 domain
#pragma unroll
    for (int r = 0; r < 4; ++r) { m_run[r] = -1e30f; l_run[r] = 0.f; }

    int ktEnd = CAUSAL ? (qt + 1) : (TB / 64);
    for (int kt = 0; kt < ktEnd; ++kt) {
        int cur = kt & 1;
        bool more = (kt + 1 < ktEnd);
        // T14: issue next tile's global loads first; latency hides under compute
        if (more) {
            gK0 += stepKV; gK1 += stepKV; gV0 += stepKV; gV1 += stepKV;
            kA = *(const int4*)gK0;
            kB = *(const int4*)gK1;
            int4 va = *(const int4*)gV0, vb2 = *(const int4*)gV1;
            const unsigned short* pa = (const unsigned short*)&va;
            const unsigned short* pb = (const unsigned short*)&vb2;
#pragma unroll
            for (int j = 0; j < 8; ++j) vp[j] = (unsigned)pa[j] | ((unsigned)pb[j] << 16);
        }

        // S = Q K^T  (16 x 64 per wave), log2 domain
        f32x4 s[4];
#pragma unroll
        for (int n = 0; n < 4; ++n) {
            f32x4 z = {};
            bf16_8 kf0 = *(const bf16_8*)(&Ks[cur][n*16 + l16][lg*8]);
            bf16_8 kf1 = *(const bf16_8*)(&Ks[cur][n*16 + l16][32 + lg*8]);
            z = __builtin_amdgcn_mfma_f32_16x16x32_bf16(qf0, kf0, z, 0, 0, 0);
            z = __builtin_amdgcn_mfma_f32_16x16x32_bf16(qf1, kf1, z, 0, 0, 0);
            s[n] = z;
        }
        // causal mask: only the diagonal tile
        if (CAUSAL && kt == qt) {
#pragma unroll
            for (int n = 0; n < 4; ++n)
#pragma unroll
                for (int r = 0; r < 4; ++r)
                    if (kt*64 + n*16 + l16 > wq + lg*4 + r) s[n][r] = -1e30f;
        }
        // row max (16-lane butterfly)
        float mx[4];
#pragma unroll
        for (int r = 0; r < 4; ++r)
            mx[r] = fmaxf(fmaxf(s[0][r], s[1][r]), fmaxf(s[2][r], s[3][r]));
#pragma unroll
        for (int off = 1; off < 16; off <<= 1)
#pragma unroll
            for (int r = 0; r < 4; ++r)
                mx[r] = fmaxf(mx[r], __shfl_xor(mx[r], off, 64));
        // T13 defer-max: rescale only when max grew by > 8 (log2)
        bool big = (mx[0] > m_run[0] + 8.f) | (mx[1] > m_run[1] + 8.f) |
                   (mx[2] > m_run[2] + 8.f) | (mx[3] > m_run[3] + 8.f);
        if (__any(big)) {
#pragma unroll
            for (int r = 0; r < 4; ++r) {
                float mnew = fmaxf(m_run[r], mx[r]);
                float sf = EXP2(m_run[r] - mnew);
                m_run[r] = mnew;
                l_run[r] *= sf;
#pragma unroll
                for (int n = 0; n < 4; ++n) o[n][r] *= sf;
            }
        }
        // P = 2^(s - m) -> LDS bf16 (wave-private; lgkmcnt orders)
#pragma unroll
        for (int n = 0; n < 4; ++n)
#pragma unroll
            for (int r = 0; r < 4; ++r)
                Ps[wave][lg*4 + r][n*16 + l16] = (__bf16)EXP2(s[n][r] - m_run[r]);

        // O += P @ V ; row-sum of P via ones-MFMA
        f32x4 zsum = {};
#pragma unroll
        for (int kk = 0; kk < 2; ++kk) {
            bf16_8 pa = *(const bf16_8*)(&Ps[wave][l16][kk*32 + lg*8]);
            zsum = __builtin_amdgcn_mfma_f32_16x16x32_bf16(pa, vones, zsum, 0, 0, 0);
#pragma unroll
            for (int n = 0; n < 4; ++n) {
                bf16_8 vf = *(const bf16_8*)(&Vt[cur][n*16 + l16][kk*32 + lg*8]);
                o[n] = __builtin_amdgcn_mfma_f32_16x16x32_bf16(pa, vf, o[n], 0, 0, 0);
            }
        }
#pragma unroll
        for (int r = 0; r < 4; ++r) l_run[r] += zsum[r];

        // write next tile into the other buffer (its last readers synced at
        // the previous barrier); one barrier publishes it for iteration kt+1
        if (more) {
            *(int4*)(&Ks[cur ^ 1][kr][kc])      = kA;
            *(int4*)(&Ks[cur ^ 1][kr + 32][kc]) = kB;
#pragma unroll
            for (int j = 0; j < 8; ++j)
                *(unsigned*)(&Vt[cur ^ 1][vd0 + j][vk2]) = vp[j];
        }
        __syncthreads();
    }

    // epilogue: O / l -> Y (bf16, [token][h*64+d])
#pragma unroll
    for (int r = 0; r < 4; ++r) {
        float rl = 1.0f / l_run[r];
        int token = b * TB + wq + lg*4 + r;
#pragma unroll
        for (int n = 0; n < 4; ++n)
            Yp[(size_t)token * C_EMBD + h * HD + n*16 + l16] = f2bf(o[n][r] * rl);
    }
}

// ---------------- LayerNorm over C=768, one block per row ----------------
template<bool WF32, bool WBF16>
__global__ __launch_bounds__(256) void k_ln(const float* __restrict__ in,
                                            const float* __restrict__ g,
                                            const float* __restrict__ bb,
                                            float* __restrict__ outf,
                                            unsigned short* __restrict__ outb) {
    int row = blockIdx.x;
    const float* x = in + (size_t)row * C_EMBD;
    float v[3], s1 = 0.f, s2 = 0.f;
#pragma unroll
    for (int i = 0; i < 3; ++i) {
        v[i] = x[threadIdx.x + i * 256];
        s1 += v[i];
        s2 += v[i] * v[i];
    }
#pragma unroll
    for (int off = 1; off < 64; off <<= 1) {
        s1 += __shfl_xor(s1, off, 64);
        s2 += __shfl_xor(s2, off, 64);
    }
    __shared__ float red[8];
    int wave = threadIdx.x >> 6, lane = threadIdx.x & 63;
    if (lane == 0) { red[wave] = s1; red[4 + wave] = s2; }
    __syncthreads();
    s1 = red[0] + red[1] + red[2] + red[3];
    s2 = red[4] + red[5] + red[6] + red[7];
    float mu  = s1 * (1.f / C_EMBD);
    float var = s2 * (1.f / C_EMBD) - mu * mu;
    float rs  = rsqrtf(var + 1e-5f);
#pragma unroll
    for (int i = 0; i < 3; ++i) {
        int c = threadIdx.x + i * 256;
        float y = (v[i] - mu) * rs * g[c] + bb[c];
        if (WF32)  outf[(size_t)row * C_EMBD + c] = y;
        if (WBF16) outb[(size_t)row * C_EMBD + c] = f2bf(y);
    }
}

// ---------------------------------------------------------------------------
extern "C" void kernel_launch(void* const* d_in, const int* in_sizes, int n_in,
                              void* d_out, int out_size, void* d_ws, size_t ws_size,
                              hipStream_t stream) {
    (void)in_sizes; (void)n_in; (void)out_size; (void)ws_size;
    const float* x      = (const float*)d_in[0];
    const float* enc    = (const float*)d_in[1];
    const float* ln1_g  = (const float*)d_in[2];
    const float* ln1_b  = (const float*)d_in[3];
    const float* qkv_w  = (const float*)d_in[4];
    const float* qkv_b  = (const float*)d_in[5];
    const float* proj_w = (const float*)d_in[6];
    const float* proj_b = (const float*)d_in[7];
    const float* ln2_g  = (const float*)d_in[8];
    const float* ln2_b  = (const float*)d_in[9];
    const float* caq_w  = (const float*)d_in[10];
    const float* caq_b  = (const float*)d_in[11];
    const float* cak_w  = (const float*)d_in[12];
    const float* cak_b  = (const float*)d_in[13];
    const float* cav_w  = (const float*)d_in[14];
    const float* cav_b  = (const float*)d_in[15];
    const float* cao_w  = (const float*)d_in[16];
    const float* cao_b  = (const float*)d_in[17];
    const float* ln3_g  = (const float*)d_in[18];
    const float* ln3_b  = (const float*)d_in[19];
    const float* fc_w   = (const float*)d_in[20];
    const float* fc_b   = (const float*)d_in[21];
    const float* fc2_w  = (const float*)d_in[22];
    const float* fc2_b  = (const float*)d_in[23];
    float* out = (float*)d_out;

    char* ws = (char*)d_ws;
    auto us = [&](size_t off) { return (unsigned short*)(ws + off); };
    auto fl = [&](size_t off) { return (float*)(ws + off); };

    // arena offsets (bytes, all 256-aligned)
    const size_t O_WQKV  = 0;            // 2304x768 bf16
    const size_t O_WPROJ = 3538944;      // 768x768
    const size_t O_WCQ   = 4718592;
    const size_t O_WCK   = 5898240;      // [Wck|Wcv] contiguous -> 1536x768
    const size_t O_WCV   = 7077888;
    const size_t O_WCO   = 8257536;
    const size_t O_WFC   = 9437184;      // 3072x768
    const size_t O_WFC2  = 14155776;     // 768x3072
    const size_t O_XBF   = 18874368;     // 4096x768 bf16
    const size_t O_ENCBF = 25165824;
    const size_t O_QKVBF = 31457280;     // 4096x2304 bf16 (later cq + [ck|cv])
    const size_t O_Q2    = O_QKVBF;
    const size_t O_KV2   = O_QKVBF + 6291456;   // 4096x1536 bf16 combined
    const size_t O_YBF   = 50331648;     // 4096x768 bf16 (attn out, reused)
    const size_t O_RESF  = 56623104;     // 4096x768 f32 (pre-LN, reused 3x)
    const size_t O_X1F   = 69206016;
    const size_t O_X1BF  = 81788928;
    const size_t O_X2F   = 88080384;
    const size_t O_X2BF  = 100663296;
    const size_t O_HBF   = 106954752;    // 4096x3072 bf16 (dead until step 11;
    const size_t O_BKV   = O_HBF;        //  bias staging lives here early)
    const size_t O_BQKV  = O_HBF + 8192;
    const size_t O_BCQ   = O_HBF + 20480;

    const float SC2 = 0.125f * 1.44269504f;   // scale * log2(e), folded into Q path

    // 1+2) fused preprocessing: all transposes + converts + bias staging
    k_preproc<<<15375, 256, 0, stream>>>(
        x, enc, qkv_w, proj_w, caq_w, cak_w, cav_w, cao_w, fc_w, fc2_w,
        qkv_b, caq_b, cak_b, cav_b,
        us(O_XBF), us(O_ENCBF),
        us(O_WQKV), us(O_WPROJ), us(O_WCQ), us(O_WCK),
        us(O_WCV), us(O_WCO), us(O_WFC), us(O_WFC2),
        fl(O_BQKV), fl(O_BKV), fl(O_BCQ), SC2);

    // 3) qkv = x @ Wqkv' + b'      (bf16 out; Q cols pre-scaled)
    k_gemm_bt<128, true,  false, false><<<dim3(32, 18), 256, 0, stream>>>(
        us(O_XBF), us(O_WQKV), fl(O_BQKV), nullptr, us(O_QKVBF), MTOK, 2304, 768);
    // 4) self-attention (causal, reversed-qt)
    k_attn<true><<<dim3(TB/64, BB*NHEAD), 256, 0, stream>>>(
        us(O_QKVBF), us(O_QKVBF) + 768, us(O_QKVBF) + 1536, us(O_YBF), 2304, 2304);
    // 5) proj + bias + residual(x) -> fp32
    k_gemm_bt<64, false, true,  false><<<dim3(64, 6), 256, 0, stream>>>(
        us(O_YBF), us(O_WPROJ), proj_b, x, fl(O_RESF), MTOK, 768, 768);
    // 6) LN1 -> x1 (f32 + bf16)
    k_ln<true, true><<<MTOK, 256, 0, stream>>>(fl(O_RESF), ln1_g, ln1_b, fl(O_X1F), us(O_X1BF));
    // 7) cross-attn projections: cq (pre-scaled) ; [ck|cv] fused (N=1536)
    k_gemm_bt<64, true,  false, false><<<dim3(64, 6), 256, 0, stream>>>(
        us(O_X1BF),  us(O_WCQ), fl(O_BCQ), nullptr, us(O_Q2), MTOK, 768, 768);
    k_gemm_bt<128, true,  false, false><<<dim3(32, 12), 256, 0, stream>>>(
        us(O_ENCBF), us(O_WCK), fl(O_BKV), nullptr, us(O_KV2), MTOK, 1536, 768);
    // 8) cross-attention (non-causal): K at col 0, V at col 768, stride 1536
    k_attn<false><<<dim3(TB/64, BB*NHEAD), 256, 0, stream>>>(
        us(O_Q2), us(O_KV2), us(O_KV2) + 768, us(O_YBF), 768, 1536);
    // 9) ca_o + bias + residual(x1) -> fp32
    k_gemm_bt<64, false, true,  false><<<dim3(64, 6), 256, 0, stream>>>(
        us(O_YBF), us(O_WCO), cao_b, fl(O_X1F), fl(O_RESF), MTOK, 768, 768);
    // 10) LN2 -> x2
    k_ln<true, true><<<MTOK, 256, 0, stream>>>(fl(O_RESF), ln2_g, ln2_b, fl(O_X2F), us(O_X2BF));
    // 11) fc + bias + relu -> bf16
    k_gemm_bt<128, true,  false, true ><<<dim3(32, 24), 256, 0, stream>>>(
        us(O_X2BF), us(O_WFC), fc_b, nullptr, us(O_HBF), MTOK, 3072, 768);
    // 12) fc2 + bias + residual(x2) -> fp32
    k_gemm_bt<64, false, true,  false><<<dim3(64, 6), 256, 0, stream>>>(
        us(O_HBF), us(O_WFC2), fc2_b, fl(O_X2F), fl(O_RESF), MTOK, 768, 3072);
    // 13) LN3 -> out (fp32 only)
    k_ln<true, false><<<MTOK, 256, 0, stream>>>(fl(O_RESF), ln3_g, ln3_b, out, nullptr);
}

// Round 9
// 474.231 us; speedup vs baseline: 1.0978x; 1.0591x over previous
//
#include <hip/hip_runtime.h>

// ---------------------------------------------------------------------------
// DecoderBlock: B=2, T=2048, C=768, H=12, d=64
// GEMMs: bf16 MFMA, m97-style global_load_lds staging; BM/BN/BK templated.
//   qkv+kv fused in one dual launch (960 blocks); N=768 GEMMs use 64x64 tiles
//   (768 blocks, 3/CU) to fix the 0.75-1.5 blocks/CU occupancy starvation.
// Attention: flash-style, 4 waves x 16 q-rows, KV tile 64, double-buffered
// LDS, one barrier/tile; Q pre-scaled (log2 domain), diagonal-only causal
// mask, defer-max (T13), reg-staged prefetch (T14).
// ---------------------------------------------------------------------------

#define C_EMBD 768
#define NHEAD  12
#define HD     64
#define TB     2048
#define BB     2
#define MTOK   (BB*TB)   // 4096 tokens

typedef __bf16 bf16_8 __attribute__((ext_vector_type(8)));
typedef float  f32x4  __attribute__((ext_vector_type(4)));

#if __has_builtin(__builtin_amdgcn_exp2f)
#define EXP2(x) __builtin_amdgcn_exp2f(x)
#else
#define EXP2(x) exp2f(x)
#endif

__device__ __forceinline__ unsigned short f2bf(float f) {
    union { __bf16 h; unsigned short u; } c;
    c.h = (__bf16)f;            // packed cvt (RNE)
    return c.u;
}

#define GLOAD_LDS16(gsrc, ldst) \
    __builtin_amdgcn_global_load_lds( \
        (const __attribute__((address_space(1))) void*)(gsrc), \
        (__attribute__((address_space(3))) void*)(ldst), 16, 0, 0)

// ---------------- fused preprocessing ----------------
__global__ __launch_bounds__(256) void k_preproc(
        const float* __restrict__ x,     const float* __restrict__ enc,
        const float* __restrict__ qkv_w, const float* __restrict__ proj_w,
        const float* __restrict__ caq_w, const float* __restrict__ cak_w,
        const float* __restrict__ cav_w, const float* __restrict__ cao_w,
        const float* __restrict__ fc_w,  const float* __restrict__ fc2_w,
        const float* __restrict__ qkv_b, const float* __restrict__ caq_b,
        const float* __restrict__ cak_b, const float* __restrict__ cav_b,
        unsigned short* __restrict__ xbf,  unsigned short* __restrict__ encbf,
        unsigned short* __restrict__ wqkv, unsigned short* __restrict__ wproj,
        unsigned short* __restrict__ wcq,  unsigned short* __restrict__ wck,
        unsigned short* __restrict__ wcv,  unsigned short* __restrict__ wco,
        unsigned short* __restrict__ wfc,  unsigned short* __restrict__ wfc2,
        float* __restrict__ bqkv, float* __restrict__ bkv, float* __restrict__ bcq,
        float sc2) {
    __shared__ float tile[32][33];
    int b = blockIdx.x, tid = threadIdx.x;
    if (b < 9216) {
        const float* W; unsigned short* Wt; int K, N, t; float sc; int slim;
        if      (b < 1728) { W=qkv_w;  Wt=wqkv;  K=768;  N=2304; t=b;      sc=sc2; slim=768; }
        else if (b < 2304) { W=proj_w; Wt=wproj; K=768;  N=768;  t=b-1728; sc=1.f; slim=0;   }
        else if (b < 2880) { W=caq_w;  Wt=wcq;   K=768;  N=768;  t=b-2304; sc=sc2; slim=768; }
        else if (b < 3456) { W=cak_w;  Wt=wck;   K=768;  N=768;  t=b-2880; sc=1.f; slim=0;   }
        else if (b < 4032) { W=cav_w;  Wt=wcv;   K=768;  N=768;  t=b-3456; sc=1.f; slim=0;   }
        else if (b < 4608) { W=cao_w;  Wt=wco;   K=768;  N=768;  t=b-4032; sc=1.f; slim=0;   }
        else if (b < 6912) { W=fc_w;   Wt=wfc;   K=768;  N=3072; t=b-4608; sc=1.f; slim=0;   }
        else               { W=fc2_w;  Wt=wfc2;  K=3072; N=768;  t=b-6912; sc=1.f; slim=0;   }
        int ntx = N >> 5;
        int n0 = (t % ntx) * 32, k0 = (t / ntx) * 32;
        int tx = tid & 31, ty = tid >> 5;
#pragma unroll
        for (int i = 0; i < 4; ++i)
            tile[ty + 8*i][tx] = W[(size_t)(k0 + ty + 8*i) * N + n0 + tx];
        __syncthreads();
#pragma unroll
        for (int i = 0; i < 4; ++i) {
            int nrow = n0 + ty + 8*i;
            float s = (nrow < slim) ? sc : 1.0f;
            Wt[(size_t)nrow * K + k0 + tx] = f2bf(tile[tx][ty + 8*i] * s);
        }
    } else if (b < 15360) {
        int b2 = b - 9216;
        const float* src = (b2 < 3072) ? x   : enc;
        unsigned short* dst = (b2 < 3072) ? xbf : encbf;
        int i = (b2 < 3072 ? b2 : b2 - 3072) * 256 + tid;
        float4 v = ((const float4*)src)[i];
        ushort4 o;
        o.x = f2bf(v.x); o.y = f2bf(v.y); o.z = f2bf(v.z); o.w = f2bf(v.w);
        ((ushort4*)dst)[i] = o;
    } else {
        int b3 = b - 15360;
        if (b3 < 9) {
            int i = b3 * 256 + tid;
            if (i < 2304) bqkv[i] = qkv_b[i] * (i < 768 ? sc2 : 1.0f);
        } else if (b3 < 12) {
            int i = (b3 - 9) * 256 + tid;
            if (i < 768) { bkv[i] = cak_b[i]; bkv[768 + i] = cav_b[i]; }
        } else {
            int i = (b3 - 12) * 256 + tid;
            if (i < 768) bcq[i] = caq_b[i] * sc2;
        }
    }
}

// ---------------- GEMM body: C[bm..][bn..] tile, 4 waves (2x2) --------------
template<int BM, int BN, int BK, bool OUT_BF16, bool ADD_RES, bool RELU>
__device__ __forceinline__ void gemm_body(
        unsigned short* As, unsigned short* Bs, int bm, int bn,
        const unsigned short* __restrict__ A,
        const unsigned short* __restrict__ Bt,
        const float* __restrict__ bias,
        const float* __restrict__ res,
        void* __restrict__ Cout,
        int N, int K) {
    constexpr int MF  = BM / 32, NF = BN / 32;     // fragments per wave
    constexpr int ACH = BM * BK / 8 / 256;         // A staging iters
    constexpr int BCH = BN * BK / 8 / 256;
    constexpr int CPR = BK / 8;                    // 16B chunks per row
    int tid  = threadIdx.x;
    int lane = tid & 63, wave = tid >> 6;
    int l16 = lane & 15, lg = lane >> 4;
    int wm = (wave >> 1) * (BM / 2), wn = (wave & 1) * (BN / 2);

    f32x4 acc[MF][NF] = {};

    for (int k0 = 0; k0 < K; k0 += BK) {
        __syncthreads();
#pragma unroll
        for (int i = 0; i < ACH; ++i) {
            int chunk = i * 256 + tid;
            GLOAD_LDS16(A + (size_t)(bm + chunk / CPR) * K + k0 + (chunk % CPR) * 8,
                        As + (size_t)(i * 256 + wave * 64) * 8);
        }
#pragma unroll
        for (int i = 0; i < BCH; ++i) {
            int chunk = i * 256 + tid;
            GLOAD_LDS16(Bt + (size_t)(bn + chunk / CPR) * K + k0 + (chunk % CPR) * 8,
                        Bs + (size_t)(i * 256 + wave * 64) * 8);
        }
        __syncthreads();   // drains vmcnt(0) -> LDS ready
#pragma unroll
        for (int kk = 0; kk < BK / 32; ++kk) {
            bf16_8 af[MF], bfr[NF];
#pragma unroll
            for (int m = 0; m < MF; ++m)
                af[m]  = *(const bf16_8*)(As + (size_t)(wm + m*16 + l16) * BK + kk*32 + lg * 8);
#pragma unroll
            for (int n = 0; n < NF; ++n)
                bfr[n] = *(const bf16_8*)(Bs + (size_t)(wn + n*16 + l16) * BK + kk*32 + lg * 8);
#pragma unroll
            for (int m = 0; m < MF; ++m)
#pragma unroll
                for (int n = 0; n < NF; ++n)
                    acc[m][n] = __builtin_amdgcn_mfma_f32_16x16x32_bf16(af[m], bfr[n], acc[m][n], 0, 0, 0);
        }
    }

#pragma unroll
    for (int m = 0; m < MF; ++m) {
#pragma unroll
        for (int n = 0; n < NF; ++n) {
            int col = bn + wn + n*16 + l16;
            float bv = bias[col];
#pragma unroll
            for (int r = 0; r < 4; ++r) {
                int row = bm + wm + m*16 + lg*4 + r;   // C/D: col=lane&15, row=(lane>>4)*4+reg
                float v = acc[m][n][r] + bv;
                if (ADD_RES) v += res[(size_t)row * N + col];
                if (RELU)    v = fmaxf(v, 0.f);
                if (OUT_BF16) ((unsigned short*)Cout)[(size_t)row * N + col] = f2bf(v);
                else          ((float*)Cout)[(size_t)row * N + col] = v;
            }
        }
    }
}

template<int BM, int BN, int BK, bool OUT_BF16, bool ADD_RES, bool RELU>
__global__ __launch_bounds__(256) void k_gemm_bt(
        const unsigned short* __restrict__ A,
        const unsigned short* __restrict__ Bt,
        const float* __restrict__ bias,
        const float* __restrict__ res,
        void* __restrict__ Cout,
        int N, int K) {
    __shared__ unsigned short As[BM * BK];
    __shared__ unsigned short Bs[BN * BK];
    gemm_body<BM, BN, BK, OUT_BF16, ADD_RES, RELU>(
        As, Bs, blockIdx.x * BM, blockIdx.y * BN, A, Bt, bias, res, Cout, N, K);
}

// dual GEMM: y<18 -> qkv (N=2304), y>=18 -> kv (N=1536); both K=768, bf16 out
__global__ __launch_bounds__(256) void k_gemm_dual(
        const unsigned short* __restrict__ A1, const unsigned short* __restrict__ B1,
        const float* __restrict__ b1, unsigned short* __restrict__ o1,
        const unsigned short* __restrict__ A2, const unsigned short* __restrict__ B2,
        const float* __restrict__ b2, unsigned short* __restrict__ o2) {
    __shared__ unsigned short As[128 * 32];
    __shared__ unsigned short Bs[128 * 32];
    const unsigned short *A, *Bt; const float* bias; unsigned short* out; int N, bn;
    if (blockIdx.y < 18) { A = A1; Bt = B1; bias = b1; out = o1; N = 2304; bn = blockIdx.y * 128; }
    else                 { A = A2; Bt = B2; bias = b2; out = o2; N = 1536; bn = (blockIdx.y - 18) * 128; }
    gemm_body<128, 128, 32, true, false, false>(
        As, Bs, blockIdx.x * 128, bn, A, Bt, bias, nullptr, out, N, 768);
}

// ---------------- Flash attention: 4 waves x 16 q-rows, KV tile 64 ----------
// Double-buffered LDS, ONE barrier per tile. Q pre-scaled by 0.125*log2(e).
template<bool CAUSAL>
__global__ __launch_bounds__(256) void k_attn(
        const unsigned short* __restrict__ Qp,
        const unsigned short* __restrict__ Kp,
        const unsigned short* __restrict__ Vp,
        unsigned short* __restrict__ Yp,
        int strideQ, int strideKV) {
    __shared__ __bf16 Ks[2][64][72];   // K tile row-major [buf][kpos][d]
    __shared__ __bf16 Vt[2][64][72];   // V tile transposed [buf][d][kpos]
    __shared__ __bf16 Ps[4][16][72];   // per-wave P tile (wave-private)
    int tid  = threadIdx.x;
    int lane = tid & 63, wave = tid >> 6;
    int l16 = lane & 15, lg = lane >> 4;
    int bh = blockIdx.y;
    int b = bh / NHEAD, h = bh - b * NHEAD;
    // causal: heaviest q-tiles first (tail-balance)
    int qt = CAUSAL ? (gridDim.x - 1 - blockIdx.x) : blockIdx.x;
    int wq = qt * 64 + wave * 16;              // this wave's q strip start

    const unsigned short* Qb = Qp + (size_t)b * TB * strideQ  + h * HD;
    const unsigned short* Kb = Kp + (size_t)b * TB * strideKV + h * HD;
    const unsigned short* Vb = Vp + (size_t)b * TB * strideKV + h * HD;

    // Q fragments (A-operand: row=l16, k=lg*8..)
    bf16_8 qf0 = *(const bf16_8*)(Qb + (size_t)(wq + l16) * strideQ + lg * 8);
    bf16_8 qf1 = *(const bf16_8*)(Qb + (size_t)(wq + l16) * strideQ + 32 + lg * 8);

    // all-ones B fragment: row-sum of P via MFMA
    bf16_8 vones;
#pragma unroll
    for (int j = 0; j < 8; ++j) vones[j] = (__bf16)1.0f;

    // staging assignments (constant per thread)
    int kr = tid >> 3, kc = (tid & 7) * 8;     // K: rows kr, kr+32; 8 cols at kc
    int vk2 = (tid & 31) * 2;                  // V: even k row pair
    int vd0 = (tid >> 5) * 8;                  // V: d block of 8
    const size_t stepKV = (size_t)64 * strideKV;

    const unsigned short* gK0 = Kb + (size_t)kr  * strideKV + kc;
    const unsigned short* gK1 = gK0 + (size_t)32 * strideKV;
    const unsigned short* gV0 = Vb + (size_t)vk2 * strideKV + vd0;
    const unsigned short* gV1 = gV0 + strideKV;

    // prologue: load tile 0 into registers, write buffer 0, one barrier
    int4 kA = *(const int4*)gK0;
    int4 kB = *(const int4*)gK1;
    unsigned vp[8];
    {
        int4 va = *(const int4*)gV0, vb2 = *(const int4*)gV1;
        const unsigned short* pa = (const unsigned short*)&va;
        const unsigned short* pb = (const unsigned short*)&vb2;
#pragma unroll
        for (int j = 0; j < 8; ++j) vp[j] = (unsigned)pa[j] | ((unsigned)pb[j] << 16);
    }
    *(int4*)(&Ks[0][kr][kc])      = kA;
    *(int4*)(&Ks[0][kr + 32][kc]) = kB;
#pragma unroll
    for (int j = 0; j < 8; ++j)
        *(unsigned*)(&Vt[0][vd0 + j][vk2]) = vp[j];
    __syncthreads();

    f32x4 o[4] = {};
    float m_run[4], l_run[4];                  // log2 domain
#pragma unroll
    for (int r = 0; r < 4; ++r) { m_run[r] = -1e30f; l_run[r] = 0.f; }

    int ktEnd = CAUSAL ? (qt + 1) : (TB / 64);
    for (int kt = 0; kt < ktEnd; ++kt) {
        int cur = kt & 1;
        bool more = (kt + 1 < ktEnd);
        // T14: issue next tile's global loads first; latency hides under compute
        if (more) {
            gK0 += stepKV; gK1 += stepKV; gV0 += stepKV; gV1 += stepKV;
            kA = *(const int4*)gK0;
            kB = *(const int4*)gK1;
            int4 va = *(const int4*)gV0, vb2 = *(const int4*)gV1;
            const unsigned short* pa = (const unsigned short*)&va;
            const unsigned short* pb = (const unsigned short*)&vb2;
#pragma unroll
            for (int j = 0; j < 8; ++j) vp[j] = (unsigned)pa[j] | ((unsigned)pb[j] << 16);
        }

        // S = Q K^T  (16 x 64 per wave), log2 domain
        f32x4 s[4];
#pragma unroll
        for (int n = 0; n < 4; ++n) {
            f32x4 z = {};
            bf16_8 kf0 = *(const bf16_8*)(&Ks[cur][n*16 + l16][lg*8]);
            bf16_8 kf1 = *(const bf16_8*)(&Ks[cur][n*16 + l16][32 + lg*8]);
            z = __builtin_amdgcn_mfma_f32_16x16x32_bf16(qf0, kf0, z, 0, 0, 0);
            z = __builtin_amdgcn_mfma_f32_16x16x32_bf16(qf1, kf1, z, 0, 0, 0);
            s[n] = z;
        }
        // causal mask: only the diagonal tile
        if (CAUSAL && kt == qt) {
#pragma unroll
            for (int n = 0; n < 4; ++n)
#pragma unroll
                for (int r = 0; r < 4; ++r)
                    if (kt*64 + n*16 + l16 > wq + lg*4 + r) s[n][r] = -1e30f;
        }
        // row max (16-lane butterfly)
        float mx[4];
#pragma unroll
        for (int r = 0; r < 4; ++r)
            mx[r] = fmaxf(fmaxf(s[0][r], s[1][r]), fmaxf(s[2][r], s[3][r]));
#pragma unroll
        for (int off = 1; off < 16; off <<= 1)
#pragma unroll
            for (int r = 0; r < 4; ++r)
                mx[r] = fmaxf(mx[r], __shfl_xor(mx[r], off, 64));
        // T13 defer-max: rescale only when max grew by > 8 (log2)
        bool big = (mx[0] > m_run[0] + 8.f) | (mx[1] > m_run[1] + 8.f) |
                   (mx[2] > m_run[2] + 8.f) | (mx[3] > m_run[3] + 8.f);
        if (__any(big)) {
#pragma unroll
            for (int r = 0; r < 4; ++r) {
                float mnew = fmaxf(m_run[r], mx[r]);
                float sf = EXP2(m_run[r] - mnew);
                m_run[r] = mnew;
                l_run[r] *= sf;
#pragma unroll
                for (int n = 0; n < 4; ++n) o[n][r] *= sf;
            }
        }
        // P = 2^(s - m) -> LDS bf16 (wave-private; lgkmcnt orders)
#pragma unroll
        for (int n = 0; n < 4; ++n)
#pragma unroll
            for (int r = 0; r < 4; ++r)
                Ps[wave][lg*4 + r][n*16 + l16] = (__bf16)EXP2(s[n][r] - m_run[r]);

        // O += P @ V ; row-sum of P via ones-MFMA
        f32x4 zsum = {};
#pragma unroll
        for (int kk = 0; kk < 2; ++kk) {
            bf16_8 pa = *(const bf16_8*)(&Ps[wave][l16][kk*32 + lg*8]);
            zsum = __builtin_amdgcn_mfma_f32_16x16x32_bf16(pa, vones, zsum, 0, 0, 0);
#pragma unroll
            for (int n = 0; n < 4; ++n) {
                bf16_8 vf = *(const bf16_8*)(&Vt[cur][n*16 + l16][kk*32 + lg*8]);
                o[n] = __builtin_amdgcn_mfma_f32_16x16x32_bf16(pa, vf, o[n], 0, 0, 0);
            }
        }
#pragma unroll
        for (int r = 0; r < 4; ++r) l_run[r] += zsum[r];

        // write next tile into the other buffer; one barrier publishes it
        if (more) {
            *(int4*)(&Ks[cur ^ 1][kr][kc])      = kA;
            *(int4*)(&Ks[cur ^ 1][kr + 32][kc]) = kB;
#pragma unroll
            for (int j = 0; j < 8; ++j)
                *(unsigned*)(&Vt[cur ^ 1][vd0 + j][vk2]) = vp[j];
        }
        __syncthreads();
    }

    // epilogue: O / l -> Y (bf16, [token][h*64+d])
#pragma unroll
    for (int r = 0; r < 4; ++r) {
        float rl = 1.0f / l_run[r];
        int token = b * TB + wq + lg*4 + r;
#pragma unroll
        for (int n = 0; n < 4; ++n)
            Yp[(size_t)token * C_EMBD + h * HD + n*16 + l16] = f2bf(o[n][r] * rl);
    }
}

// ---------------- LayerNorm over C=768, one block per row ----------------
template<bool WF32, bool WBF16>
__global__ __launch_bounds__(256) void k_ln(const float* __restrict__ in,
                                            const float* __restrict__ g,
                                            const float* __restrict__ bb,
                                            float* __restrict__ outf,
                                            unsigned short* __restrict__ outb) {
    int row = blockIdx.x;
    const float* x = in + (size_t)row * C_EMBD;
    float v[3], s1 = 0.f, s2 = 0.f;
#pragma unroll
    for (int i = 0; i < 3; ++i) {
        v[i] = x[threadIdx.x + i * 256];
        s1 += v[i];
        s2 += v[i] * v[i];
    }
#pragma unroll
    for (int off = 1; off < 64; off <<= 1) {
        s1 += __shfl_xor(s1, off, 64);
        s2 += __shfl_xor(s2, off, 64);
    }
    __shared__ float red[8];
    int wave = threadIdx.x >> 6, lane = threadIdx.x & 63;
    if (lane == 0) { red[wave] = s1; red[4 + wave] = s2; }
    __syncthreads();
    s1 = red[0] + red[1] + red[2] + red[3];
    s2 = red[4] + red[5] + red[6] + red[7];
    float mu  = s1 * (1.f / C_EMBD);
    float var = s2 * (1.f / C_EMBD) - mu * mu;
    float rs  = rsqrtf(var + 1e-5f);
#pragma unroll
    for (int i = 0; i < 3; ++i) {
        int c = threadIdx.x + i * 256;
        float y = (v[i] - mu) * rs * g[c] + bb[c];
        if (WF32)  outf[(size_t)row * C_EMBD + c] = y;
        if (WBF16) outb[(size_t)row * C_EMBD + c] = f2bf(y);
    }
}

// ---------------------------------------------------------------------------
extern "C" void kernel_launch(void* const* d_in, const int* in_sizes, int n_in,
                              void* d_out, int out_size, void* d_ws, size_t ws_size,
                              hipStream_t stream) {
    (void)in_sizes; (void)n_in; (void)out_size; (void)ws_size;
    const float* x      = (const float*)d_in[0];
    const float* enc    = (const float*)d_in[1];
    const float* ln1_g  = (const float*)d_in[2];
    const float* ln1_b  = (const float*)d_in[3];
    const float* qkv_w  = (const float*)d_in[4];
    const float* qkv_b  = (const float*)d_in[5];
    const float* proj_w = (const float*)d_in[6];
    const float* proj_b = (const float*)d_in[7];
    const float* ln2_g  = (const float*)d_in[8];
    const float* ln2_b  = (const float*)d_in[9];
    const float* caq_w  = (const float*)d_in[10];
    const float* caq_b  = (const float*)d_in[11];
    const float* cak_w  = (const float*)d_in[12];
    const float* cak_b  = (const float*)d_in[13];
    const float* cav_w  = (const float*)d_in[14];
    const float* cav_b  = (const float*)d_in[15];
    const float* cao_w  = (const float*)d_in[16];
    const float* cao_b  = (const float*)d_in[17];
    const float* ln3_g  = (const float*)d_in[18];
    const float* ln3_b  = (const float*)d_in[19];
    const float* fc_w   = (const float*)d_in[20];
    const float* fc_b   = (const float*)d_in[21];
    const float* fc2_w  = (const float*)d_in[22];
    const float* fc2_b  = (const float*)d_in[23];
    float* out = (float*)d_out;

    char* ws = (char*)d_ws;
    auto us = [&](size_t off) { return (unsigned short*)(ws + off); };
    auto fl = [&](size_t off) { return (float*)(ws + off); };

    // arena offsets (bytes, all 256-aligned)
    const size_t O_WQKV  = 0;            // 2304x768 bf16
    const size_t O_WPROJ = 3538944;      // 768x768
    const size_t O_WCQ   = 4718592;
    const size_t O_WCK   = 5898240;      // [Wck|Wcv] contiguous -> 1536x768
    const size_t O_WCV   = 7077888;
    const size_t O_WCO   = 8257536;
    const size_t O_WFC   = 9437184;      // 3072x768
    const size_t O_WFC2  = 14155776;     // 768x3072
    const size_t O_XBF   = 18874368;     // 4096x768 bf16
    const size_t O_ENCBF = 25165824;
    const size_t O_QKVBF = 31457280;     // 4096x2304 bf16 (later cq)
    const size_t O_Q2    = O_QKVBF;
    const size_t O_YBF   = 50331648;     // 4096x768 bf16 (attn out, reused)
    const size_t O_RESF  = 56623104;     // 4096x768 f32 (pre-LN, reused 3x)
    const size_t O_X1F   = 69206016;
    const size_t O_X1BF  = 81788928;
    const size_t O_X2F   = 88080384;     // kv bf16 (steps 2-8), then LN2 f32
    const size_t O_KV2   = O_X2F;        //   4096x1536 bf16 = 12.58 MB exact
    const size_t O_X2BF  = 100663296;
    const size_t O_HBF   = 106954752;    // 4096x3072 bf16 (dead until step 11;
    const size_t O_BKV   = O_HBF;        //  bias staging lives here early)
    const size_t O_BQKV  = O_HBF + 8192;
    const size_t O_BCQ   = O_HBF + 20480;

    const float SC2 = 0.125f * 1.44269504f;   // scale * log2(e), folded into Q path

    // 1) fused preprocessing: all transposes + converts + bias staging
    k_preproc<<<15375, 256, 0, stream>>>(
        x, enc, qkv_w, proj_w, caq_w, cak_w, cav_w, cao_w, fc_w, fc2_w,
        qkv_b, caq_b, cak_b, cav_b,
        us(O_XBF), us(O_ENCBF),
        us(O_WQKV), us(O_WPROJ), us(O_WCQ), us(O_WCK),
        us(O_WCV), us(O_WCO), us(O_WFC), us(O_WFC2),
        fl(O_BQKV), fl(O_BKV), fl(O_BCQ), SC2);

    // 2) dual GEMM: qkv = x@Wqkv'+b' AND kv = enc@Wkv+b (independent -> fused)
    k_gemm_dual<<<dim3(32, 30), 256, 0, stream>>>(
        us(O_XBF),   us(O_WQKV), fl(O_BQKV), us(O_QKVBF),
        us(O_ENCBF), us(O_WCK),  fl(O_BKV),  us(O_KV2));
    // 3) self-attention (causal, reversed-qt)
    k_attn<true><<<dim3(TB/64, BB*NHEAD), 256, 0, stream>>>(
        us(O_QKVBF), us(O_QKVBF) + 768, us(O_QKVBF) + 1536, us(O_YBF), 2304, 2304);
    // 4) proj + bias + residual(x) -> fp32   (64x64 tiles, 768 blocks)
    k_gemm_bt<64, 64, 32, false, true,  false><<<dim3(64, 12), 256, 0, stream>>>(
        us(O_YBF), us(O_WPROJ), proj_b, x, fl(O_RESF), 768, 768);
    // 5) LN1 -> x1 (f32 + bf16)
    k_ln<true, true><<<MTOK, 256, 0, stream>>>(fl(O_RESF), ln1_g, ln1_b, fl(O_X1F), us(O_X1BF));
    // 6) cq = x1 @ Wcq' + b'  (pre-scaled)
    k_gemm_bt<64, 64, 32, true,  false, false><<<dim3(64, 12), 256, 0, stream>>>(
        us(O_X1BF), us(O_WCQ), fl(O_BCQ), nullptr, us(O_Q2), 768, 768);
    // 7) cross-attention (non-causal): K at col 0, V at col 768, stride 1536
    k_attn<false><<<dim3(TB/64, BB*NHEAD), 256, 0, stream>>>(
        us(O_Q2), us(O_KV2), us(O_KV2) + 768, us(O_YBF), 768, 1536);
    // 8) ca_o + bias + residual(x1) -> fp32
    k_gemm_bt<64, 64, 32, false, true,  false><<<dim3(64, 12), 256, 0, stream>>>(
        us(O_YBF), us(O_WCO), cao_b, fl(O_X1F), fl(O_RESF), 768, 768);
    // 9) LN2 -> x2 (overwrites the consumed kv region)
    k_ln<true, true><<<MTOK, 256, 0, stream>>>(fl(O_RESF), ln2_g, ln2_b, fl(O_X2F), us(O_X2BF));
    // 10) fc + bias + relu -> bf16
    k_gemm_bt<128, 128, 32, true,  false, true ><<<dim3(32, 24), 256, 0, stream>>>(
        us(O_X2BF), us(O_WFC), fc_b, nullptr, us(O_HBF), 3072, 768);
    // 11) fc2 + bias + residual(x2) -> fp32
    k_gemm_bt<64, 64, 32, false, true,  false><<<dim3(64, 12), 256, 0, stream>>>(
        us(O_HBF), us(O_WFC2), fc2_b, fl(O_X2F), fl(O_RESF), 768, 3072);
    // 12) LN3 -> out (fp32 only)
    k_ln<true, false><<<MTOK, 256, 0, stream>>>(fl(O_RESF), ln3_g, ln3_b, out, nullptr);
}